// Round 2
// baseline (547.465 us; speedup 1.0000x reference)
//
#include <hip/hip_runtime.h>
#include <hip/hip_cooperative_groups.h>

#define MAXV 127.0f
#define Mdim 8192
#define Ndim 4096
#define Kdim 4096

// ---- elementwise geometry ----
#define EW_GRID 2048
#define EW_BLOCK 256
#define EW_STRIDE (EW_GRID * EW_BLOCK)
#define FEW_GRID 1024                 // cooperative: 4 blocks/CU guaranteed
#define FEW_THREADS (FEW_GRID * 256)  // 262144
#define XG4 (Mdim * Kdim / 16)        // float4-groups-of-4 in x: 2097152 -> 8 rounds
#define WG4 (Ndim * Kdim / 16)        // 1048576 -> 4 rounds

typedef __attribute__((ext_vector_type(4))) int int32x4;

__device__ __forceinline__ void async_load16(const void* g, void* l) {
  __builtin_amdgcn_global_load_lds(
      (const __attribute__((address_space(1))) unsigned int*)g,
      (__attribute__((address_space(3))) unsigned int*)l, 16, 0, 0);
}

__device__ __forceinline__ float amax4(float4 v) {
  return fmaxf(fmaxf(fabsf(v.x), fabsf(v.y)), fmaxf(fabsf(v.z), fabsf(v.w)));
}

__device__ __forceinline__ int pack4(float4 v, float s) {
  int a = (int)fminf(fmaxf(rintf(v.x * s), -MAXV), MAXV);
  int b = (int)fminf(fmaxf(rintf(v.y * s), -MAXV), MAXV);
  int c = (int)fminf(fmaxf(rintf(v.z * s), -MAXV), MAXV);
  int d = (int)fminf(fmaxf(rintf(v.w * s), -MAXV), MAXV);
  return (a & 255) | ((b & 255) << 8) | ((c & 255) << 16) | (d << 24);
}

// ---------------------------------------------------------------------------
// Fused memily amax+quant: one cooperative kernel, grid.sync between passes.
// 64 B/thread/round loads, 16 B/lane quant stores. VGPR kept modest so
// 4 blocks/CU co-residency holds (1024 blocks exactly fill the chip).
// ---------------------------------------------------------------------------
__global__ __launch_bounds__(256) void fused_ew_kernel(
    const float4* __restrict__ x, const float4* __restrict__ w,
    int* __restrict__ amax_bits, int32x4* __restrict__ qx,
    int32x4* __restrict__ qw) {
  const int t = blockIdx.x * 256 + threadIdx.x;
  float mx = 0.0f, mw = 0.0f;
#pragma unroll 2
  for (int r = 0; r < 8; r++) {
    const float4* p = x + 4 * ((size_t)r * FEW_THREADS + t);
    float4 a = p[0], b = p[1], c = p[2], d = p[3];
    mx = fmaxf(mx, fmaxf(fmaxf(amax4(a), amax4(b)), fmaxf(amax4(c), amax4(d))));
  }
#pragma unroll 2
  for (int r = 0; r < 4; r++) {
    const float4* p = w + 4 * ((size_t)r * FEW_THREADS + t);
    float4 a = p[0], b = p[1], c = p[2], d = p[3];
    mw = fmaxf(mw, fmaxf(fmaxf(amax4(a), amax4(b)), fmaxf(amax4(c), amax4(d))));
  }
  for (int off = 32; off > 0; off >>= 1) {
    mx = fmaxf(mx, __shfl_down(mx, off));
    mw = fmaxf(mw, __shfl_down(mw, off));
  }
  __shared__ float sm[8];
  if ((threadIdx.x & 63) == 0) {
    sm[threadIdx.x >> 6] = mx;
    sm[4 + (threadIdx.x >> 6)] = mw;
  }
  __syncthreads();
  if (threadIdx.x == 0) {
    atomicMax(amax_bits,
              __float_as_int(fmaxf(fmaxf(sm[0], sm[1]), fmaxf(sm[2], sm[3]))));
    atomicMax(amax_bits + 1,
              __float_as_int(fmaxf(fmaxf(sm[4], sm[5]), fmaxf(sm[6], sm[7]))));
  }
  cooperative_groups::this_grid().sync();
  const float sx = MAXV / __int_as_float(amax_bits[0]);
  const float sw = MAXV / __int_as_float(amax_bits[1]);
#pragma unroll 2
  for (int r = 0; r < 8; r++) {
    const size_t g = (size_t)r * FEW_THREADS + t;
    const float4* p = x + 4 * g;
    int32x4 q;
    q[0] = pack4(p[0], sx);
    q[1] = pack4(p[1], sx);
    q[2] = pack4(p[2], sx);
    q[3] = pack4(p[3], sx);
    qx[g] = q;
  }
#pragma unroll 2
  for (int r = 0; r < 4; r++) {
    const size_t g = (size_t)r * FEW_THREADS + t;
    const float4* p = w + 4 * g;
    int32x4 q;
    q[0] = pack4(p[0], sw);
    q[1] = pack4(p[1], sw);
    q[2] = pack4(p[2], sw);
    q[3] = pack4(p[3], sw);
    qw[g] = q;
  }
}

// ---- fallback pair (proven path) ----
__global__ __launch_bounds__(EW_BLOCK) void amax_both_kernel(
    const float4* __restrict__ x, const float4* __restrict__ w,
    int* __restrict__ out_bits) {
  const int t = blockIdx.x * EW_BLOCK + threadIdx.x;
  float mx = 0.0f, mw = 0.0f;
#pragma unroll
  for (int i = 0; i < 4; i++) {
    float4 a = x[t + (4 * i + 0) * EW_STRIDE];
    float4 b = x[t + (4 * i + 1) * EW_STRIDE];
    float4 c = x[t + (4 * i + 2) * EW_STRIDE];
    float4 d = x[t + (4 * i + 3) * EW_STRIDE];
    mx = fmaxf(mx, fmaxf(fmaxf(amax4(a), amax4(b)), fmaxf(amax4(c), amax4(d))));
  }
#pragma unroll
  for (int i = 0; i < 2; i++) {
    float4 a = w[t + (4 * i + 0) * EW_STRIDE];
    float4 b = w[t + (4 * i + 1) * EW_STRIDE];
    float4 c = w[t + (4 * i + 2) * EW_STRIDE];
    float4 d = w[t + (4 * i + 3) * EW_STRIDE];
    mw = fmaxf(mw, fmaxf(fmaxf(amax4(a), amax4(b)), fmaxf(amax4(c), amax4(d))));
  }
  for (int off = 32; off > 0; off >>= 1) {
    mx = fmaxf(mx, __shfl_down(mx, off));
    mw = fmaxf(mw, __shfl_down(mw, off));
  }
  __shared__ float sm[8];
  if ((threadIdx.x & 63) == 0) {
    sm[threadIdx.x >> 6] = mx;
    sm[4 + (threadIdx.x >> 6)] = mw;
  }
  __syncthreads();
  if (threadIdx.x == 0) {
    atomicMax(out_bits,
              __float_as_int(fmaxf(fmaxf(sm[0], sm[1]), fmaxf(sm[2], sm[3]))));
    atomicMax(out_bits + 1,
              __float_as_int(fmaxf(fmaxf(sm[4], sm[5]), fmaxf(sm[6], sm[7]))));
  }
}

__device__ __forceinline__ char4 quant4(float4 v, float s) {
  char4 q;
  q.x = (signed char)(int)fminf(fmaxf(rintf(v.x * s), -MAXV), MAXV);
  q.y = (signed char)(int)fminf(fmaxf(rintf(v.y * s), -MAXV), MAXV);
  q.z = (signed char)(int)fminf(fmaxf(rintf(v.z * s), -MAXV), MAXV);
  q.w = (signed char)(int)fminf(fmaxf(rintf(v.w * s), -MAXV), MAXV);
  return q;
}

__global__ __launch_bounds__(EW_BLOCK) void quant_both_kernel(
    const float4* __restrict__ x, const float4* __restrict__ w,
    const int* __restrict__ amax_bits, char4* __restrict__ qx,
    char4* __restrict__ qw) {
  const float sx = MAXV / __int_as_float(amax_bits[0]);
  const float sw = MAXV / __int_as_float(amax_bits[1]);
  const int t = blockIdx.x * EW_BLOCK + threadIdx.x;
#pragma unroll
  for (int i = 0; i < 4; i++) {
    int i0 = t + (4 * i + 0) * EW_STRIDE, i1 = t + (4 * i + 1) * EW_STRIDE;
    int i2 = t + (4 * i + 2) * EW_STRIDE, i3 = t + (4 * i + 3) * EW_STRIDE;
    float4 a = x[i0], b = x[i1], c = x[i2], d = x[i3];
    qx[i0] = quant4(a, sx);
    qx[i1] = quant4(b, sx);
    qx[i2] = quant4(c, sx);
    qx[i3] = quant4(d, sx);
  }
#pragma unroll
  for (int i = 0; i < 2; i++) {
    int i0 = t + (4 * i + 0) * EW_STRIDE, i1 = t + (4 * i + 1) * EW_STRIDE;
    int i2 = t + (4 * i + 2) * EW_STRIDE, i3 = t + (4 * i + 3) * EW_STRIDE;
    float4 a = w[i0], b = w[i1], c = w[i2], d = w[i3];
    qw[i0] = quant4(a, sw);
    qw[i1] = quant4(b, sw);
    qw[i2] = quant4(c, sw);
    qw[i3] = quant4(d, sw);
  }
}

// ---------------------------------------------------------------------------
// 256x256 8-phase i8 GEMM. Change vs R1: SYNC_MID no longer force-drains
// lgkmcnt(0) — ds_reads are C-level loads, so the compiler emits counted
// lgkmcnt waits per consuming MFMA (m97 evidence), overlapping the LDS
// drain with the MFMA cluster. Barriers / vmcnt fences / setprio unchanged.
// Safety: every phase's loads are consumed by that phase's MFMAs, so all
// waits retire before the phase-end barrier; DMA overwrites of any LDS
// region remain >=2 barriers after its last read. vmcnt asm keeps the
// "memory" clobber = the only compiler fence needed per tile.
// ---------------------------------------------------------------------------
#define BM 256
#define BN 256
#define BKB 128
#define HALF 16384
#define NIT 15  // main iterations; last iteration (tiles 30,31) is peeled

#define LDSA(buf) (lds + ((buf) * 4 + wm) * HALF)
#define LDSB(buf) (lds + ((buf) * 4 + 2 + (wn >> 1)) * HALF)

#define STG_A(buf, h, kt)                                          \
  {                                                                \
    signed char* d = lds + ((buf) * 4 + (h)) * HALF + wdst;        \
    const signed char* s = aS + (h) * HSK + (size_t)(kt) * BKB;    \
    async_load16(s, d);                                            \
    async_load16(s + 64 * (size_t)Kdim, d + 8192);                 \
  }
#define STG_B(buf, h, kt)                                          \
  {                                                                \
    signed char* d = lds + ((buf) * 4 + 2 + (h)) * HALF + wdst;    \
    const signed char* s = bS + (h) * HSK + (size_t)(kt) * BKB;    \
    async_load16(s, d);                                            \
    async_load16(s + 64 * (size_t)Kdim, d + 8192);                 \
  }

#define LOAD_A(buf, mh)                                            \
  {                                                                \
    const signed char* ab = LDSA(buf) + (mh) * 8192;               \
    _Pragma("unroll") for (int mi = 0; mi < 4; mi++) {             \
      afr[mi][0] = *(const int32x4*)(ab + mi * 2048 + aoff0);      \
      afr[mi][1] = *(const int32x4*)(ab + mi * 2048 + aoff1);      \
    }                                                              \
  }
#define LOAD_B(buf, g)                                             \
  {                                                                \
    const signed char* bb = LDSB(buf) + brow0 + (g) * 4096;        \
    _Pragma("unroll") for (int j = 0; j < 2; j++) {                \
      bfr[(g) * 2 + j][0] = *(const int32x4*)(bb + j * 2048 + aoff0); \
      bfr[(g) * 2 + j][1] = *(const int32x4*)(bb + j * 2048 + aoff1); \
    }                                                              \
  }

#define MFMA_Q(ma, nb)                                                        \
  _Pragma("unroll") for (int mi = 0; mi < 4; mi++)                            \
  _Pragma("unroll") for (int nj = 0; nj < 2; nj++)                            \
  _Pragma("unroll") for (int ks = 0; ks < 2; ks++)                            \
      acc[(ma) * 4 + mi][(nb) * 2 + nj] =                                     \
          __builtin_amdgcn_mfma_i32_16x16x64_i8(                              \
              afr[mi][ks], bfr[(nb) * 2 + nj][ks],                            \
              acc[(ma) * 4 + mi][(nb) * 2 + nj], 0, 0, 0);

#define SYNC_MID()              \
  __builtin_amdgcn_s_barrier(); \
  __builtin_amdgcn_s_setprio(1);

#define PH_END()                \
  __builtin_amdgcn_s_setprio(0); \
  __builtin_amdgcn_s_barrier();

#define PH_END_V(n)                                      \
  __builtin_amdgcn_s_setprio(0);                         \
  asm volatile("s_waitcnt vmcnt(" #n ")" ::: "memory");  \
  __builtin_amdgcn_s_barrier();

__global__ __launch_bounds__(512, 2) void gemm_i8_kernel(
    const signed char* __restrict__ Aq, const signed char* __restrict__ Bq,
    const float* __restrict__ bias, const int* __restrict__ amax_bits,
    float* __restrict__ out) {
  __shared__ signed char lds[8 * HALF];  // 128 KiB

  const int tid = threadIdx.x;
  const int lane = tid & 63;
  const int w = tid >> 6;
  const int wm = w >> 2;  // 0..1
  const int wn = w & 3;   // 0..3

  const int m0 = blockIdx.y * BM;
  const int n0 = blockIdx.x * BN;

  // staging: thread covers rows r0 and r0+64 of a half, same (swizzled) col
  const int r0 = tid >> 3;
  const int gcol = ((tid & 7) * 16) ^ ((r0 & 7) << 4);
  const signed char* aS = Aq + (size_t)(m0 + r0) * Kdim + gcol;
  const signed char* bS = Bq + (size_t)(n0 + r0) * Kdim + gcol;
  const size_t HSK = (size_t)128 * Kdim;
  const int wdst = w * 1024;  // wave-uniform LDS dest

  // ds-read offsets (row = lane&15 within frag; swizzle uses lane&7)
  const int aoff0 =
      (lane & 15) * 128 + (((lane >> 4) * 16) ^ ((lane & 7) << 4));
  const int aoff1 =
      (lane & 15) * 128 + ((64 + (lane >> 4) * 16) ^ ((lane & 7) << 4));
  const int brow0 = (wn & 1) * 8192;

  int32x4 acc[8][4] = {};
  int32x4 afr[4][2], bfr[4][2];

  // prologue: tile0 -> buf0 (all halves); tile1 B-halves -> buf1
  STG_A(0, 0, 0);
  STG_A(0, 1, 0);
  STG_B(0, 0, 0);
  STG_B(0, 1, 0);
  STG_B(1, 0, 1);
  STG_B(1, 1, 1);
  asm volatile("s_waitcnt vmcnt(4)" ::: "memory");
  __builtin_amdgcn_s_barrier();

#pragma unroll 1
  for (int it = 0; it < NIT; ++it) {
    const int kt1 = 2 * it + 1, kt2 = 2 * it + 2, kt3 = 2 * it + 3;
    // phase 0: tile 2i quadrant (0,0)
    LOAD_A(0, 0); LOAD_B(0, 0); STG_A(1, 0, kt1);
    SYNC_MID(); MFMA_Q(0, 0); PH_END();
    // phase 1
    LOAD_B(0, 1); STG_A(1, 1, kt1);
    SYNC_MID(); MFMA_Q(0, 1); PH_END();
    // phase 2
    LOAD_A(0, 1); STG_B(0, 0, kt2);
    SYNC_MID(); MFMA_Q(1, 1); PH_END();
    // phase 3 (counted wait: covers tile 2i+1 A/B for phase 4)
    STG_B(0, 1, kt2);
    SYNC_MID(); MFMA_Q(1, 0); PH_END_V(4);
    // phase 4: tile 2i+1 quadrant (0,0)
    LOAD_A(1, 0); LOAD_B(1, 0); STG_A(0, 0, kt2);
    SYNC_MID(); MFMA_Q(0, 0); PH_END();
    // phase 5
    LOAD_B(1, 1); STG_A(0, 1, kt2);
    SYNC_MID(); MFMA_Q(0, 1); PH_END();
    // phase 6
    LOAD_A(1, 1); STG_B(1, 0, kt3);
    SYNC_MID(); MFMA_Q(1, 1); PH_END();
    // phase 7 (counted wait: covers tile 2i+2 for next iter phase 0)
    STG_B(1, 1, kt3);
    SYNC_MID(); MFMA_Q(1, 0); PH_END_V(4);
  }

  // peeled last iteration: tiles 30 (buf0) / 31 (buf1); only stage 31's A
  {
    LOAD_A(0, 0); LOAD_B(0, 0); STG_A(1, 0, 31);
    SYNC_MID(); MFMA_Q(0, 0); PH_END();
    LOAD_B(0, 1); STG_A(1, 1, 31);
    SYNC_MID(); MFMA_Q(0, 1); PH_END();
    LOAD_A(0, 1);
    SYNC_MID(); MFMA_Q(1, 1); PH_END();
    SYNC_MID(); MFMA_Q(1, 0); PH_END_V(0);  // full drain: no DMA in flight
    LOAD_A(1, 0); LOAD_B(1, 0);
    SYNC_MID(); MFMA_Q(0, 0); PH_END();
    LOAD_B(1, 1);
    SYNC_MID(); MFMA_Q(0, 1); PH_END();
    LOAD_A(1, 1);
    SYNC_MID(); MFMA_Q(1, 1); PH_END();
    SYNC_MID(); MFMA_Q(1, 0);
    __builtin_amdgcn_s_setprio(0);
  }

  // epilogue: dequant + bias, scalar stores coalesced across lanes
  const float sx = MAXV / __int_as_float(amax_bits[0]);
  const float sw = MAXV / __int_as_float(amax_bits[1]);
  const float inv = 1.0f / (sx * sw);
  const int crow = (lane >> 4) * 4;
  const int ccol = lane & 15;
#pragma unroll
  for (int nj = 0; nj < 4; nj++) {
    const int n = n0 + wn * 64 + nj * 16 + ccol;
    const float bv = bias[n];
#pragma unroll
    for (int a = 0; a < 8; a++) {
      const int m = m0 + wm * 128 + a * 16 + crow;
      float* op = out + (size_t)m * Ndim + n;
#pragma unroll
      for (int r = 0; r < 4; r++)
        op[(size_t)r * Ndim] = (float)acc[a][nj][r] * inv + bv;
    }
  }
}

extern "C" void kernel_launch(void* const* d_in, const int* in_sizes, int n_in,
                              void* d_out, int out_size, void* d_ws,
                              size_t ws_size, hipStream_t stream) {
  const float* x = (const float*)d_in[0];
  const float* wgt = (const float*)d_in[1];
  const float* bias = (const float*)d_in[2];
  float* out = (float*)d_out;

  int* amax = (int*)d_ws;
  signed char* qx = (signed char*)d_ws + 256;
  signed char* qw = qx + (size_t)Mdim * Kdim;

  hipMemsetAsync(amax, 0, 2 * sizeof(int), stream);

  // fused cooperative amax+quant; fall back to the proven 2-kernel path
  const float4* xp = (const float4*)x;
  const float4* wp = (const float4*)wgt;
  int* ap = amax;
  int32x4* qx4 = (int32x4*)qx;
  int32x4* qw4 = (int32x4*)qw;
  void* args[5] = {&xp, &wp, &ap, &qx4, &qw4};
  hipError_t ce = hipLaunchCooperativeKernel(
      (const void*)fused_ew_kernel, dim3(FEW_GRID), dim3(256), args, 0, stream);
  if (ce != hipSuccess) {
    hipLaunchKernelGGL(amax_both_kernel, dim3(EW_GRID), dim3(EW_BLOCK), 0,
                       stream, (const float4*)x, (const float4*)wgt, amax);
    hipLaunchKernelGGL(quant_both_kernel, dim3(EW_GRID), dim3(EW_BLOCK), 0,
                       stream, (const float4*)x, (const float4*)wgt, amax,
                       (char4*)qx, (char4*)qw);
  }

  hipLaunchKernelGGL(gemm_i8_kernel, dim3(Ndim / BN, Mdim / BM), dim3(512), 0,
                     stream, qx, qw, bias, amax, out);
}

// Round 3
// 433.461 us; speedup vs baseline: 1.2630x; 1.2630x over previous
//
#include <hip/hip_runtime.h>

#define MAXV 127.0f
#define Mdim 8192
#define Ndim 4096
#define Kdim 4096

// ---- elementwise geometry (sizes divide exactly; no tail handling) ----
#define EW_GRID 2048
#define EW_BLOCK 256
#define EW_STRIDE (EW_GRID * EW_BLOCK)  // 524288 threads

typedef __attribute__((ext_vector_type(4))) int int32x4;

__device__ __forceinline__ void async_load16(const void* g, void* l) {
  __builtin_amdgcn_global_load_lds(
      (const __attribute__((address_space(1))) unsigned int*)g,
      (__attribute__((address_space(3))) unsigned int*)l, 16, 0, 0);
}

__device__ __forceinline__ float amax4(float4 v) {
  return fmaxf(fmaxf(fabsf(v.x), fabsf(v.y)), fmaxf(fabsf(v.z), fabsf(v.w)));
}

// 8 independent float4 loads in flight per round (32 data VGPRs), lanes
// 16 B-contiguous per load instruction (proven-coalesced R1 pattern).
__global__ __launch_bounds__(EW_BLOCK) void amax_both_kernel(
    const float4* __restrict__ x, const float4* __restrict__ w,
    int* __restrict__ out_bits) {
  const int t = blockIdx.x * EW_BLOCK + threadIdx.x;
  float mx = 0.0f, mw = 0.0f;
#pragma unroll
  for (int o = 0; o < 2; o++) {  // 16 float4 over x as 2 rounds of 8
    float4 v0 = x[t + (8 * o + 0) * EW_STRIDE];
    float4 v1 = x[t + (8 * o + 1) * EW_STRIDE];
    float4 v2 = x[t + (8 * o + 2) * EW_STRIDE];
    float4 v3 = x[t + (8 * o + 3) * EW_STRIDE];
    float4 v4 = x[t + (8 * o + 4) * EW_STRIDE];
    float4 v5 = x[t + (8 * o + 5) * EW_STRIDE];
    float4 v6 = x[t + (8 * o + 6) * EW_STRIDE];
    float4 v7 = x[t + (8 * o + 7) * EW_STRIDE];
    float m0 = fmaxf(amax4(v0), amax4(v1));
    float m1 = fmaxf(amax4(v2), amax4(v3));
    float m2 = fmaxf(amax4(v4), amax4(v5));
    float m3 = fmaxf(amax4(v6), amax4(v7));
    mx = fmaxf(mx, fmaxf(fmaxf(m0, m1), fmaxf(m2, m3)));
  }
  {  // 8 float4 over w in one round of 8
    float4 v0 = w[t + 0 * EW_STRIDE];
    float4 v1 = w[t + 1 * EW_STRIDE];
    float4 v2 = w[t + 2 * EW_STRIDE];
    float4 v3 = w[t + 3 * EW_STRIDE];
    float4 v4 = w[t + 4 * EW_STRIDE];
    float4 v5 = w[t + 5 * EW_STRIDE];
    float4 v6 = w[t + 6 * EW_STRIDE];
    float4 v7 = w[t + 7 * EW_STRIDE];
    float m0 = fmaxf(amax4(v0), amax4(v1));
    float m1 = fmaxf(amax4(v2), amax4(v3));
    float m2 = fmaxf(amax4(v4), amax4(v5));
    float m3 = fmaxf(amax4(v6), amax4(v7));
    mw = fmaxf(fmaxf(m0, m1), fmaxf(m2, m3));
  }
  for (int off = 32; off > 0; off >>= 1) {
    mx = fmaxf(mx, __shfl_down(mx, off));
    mw = fmaxf(mw, __shfl_down(mw, off));
  }
  __shared__ float sm[8];
  if ((threadIdx.x & 63) == 0) {
    sm[threadIdx.x >> 6] = mx;
    sm[4 + (threadIdx.x >> 6)] = mw;
  }
  __syncthreads();
  if (threadIdx.x == 0) {
    atomicMax(out_bits,
              __float_as_int(fmaxf(fmaxf(sm[0], sm[1]), fmaxf(sm[2], sm[3]))));
    atomicMax(out_bits + 1,
              __float_as_int(fmaxf(fmaxf(sm[4], sm[5]), fmaxf(sm[6], sm[7]))));
  }
}

__device__ __forceinline__ char4 quant4(float4 v, float s) {
  char4 q;
  q.x = (signed char)(int)fminf(fmaxf(rintf(v.x * s), -MAXV), MAXV);
  q.y = (signed char)(int)fminf(fmaxf(rintf(v.y * s), -MAXV), MAXV);
  q.z = (signed char)(int)fminf(fmaxf(rintf(v.z * s), -MAXV), MAXV);
  q.w = (signed char)(int)fminf(fmaxf(rintf(v.w * s), -MAXV), MAXV);
  return q;
}

// 8-deep load rounds; reads should be LLC-warm after amax (R2 FETCH_SIZE
// evidence: second pass over x/w is served by Infinity Cache).
__global__ __launch_bounds__(EW_BLOCK) void quant_both_kernel(
    const float4* __restrict__ x, const float4* __restrict__ w,
    const int* __restrict__ amax_bits, char4* __restrict__ qx,
    char4* __restrict__ qw) {
  const float sx = MAXV / __int_as_float(amax_bits[0]);
  const float sw = MAXV / __int_as_float(amax_bits[1]);
  const int t = blockIdx.x * EW_BLOCK + threadIdx.x;
#pragma unroll
  for (int o = 0; o < 2; o++) {
    float4 v0 = x[t + (8 * o + 0) * EW_STRIDE];
    float4 v1 = x[t + (8 * o + 1) * EW_STRIDE];
    float4 v2 = x[t + (8 * o + 2) * EW_STRIDE];
    float4 v3 = x[t + (8 * o + 3) * EW_STRIDE];
    float4 v4 = x[t + (8 * o + 4) * EW_STRIDE];
    float4 v5 = x[t + (8 * o + 5) * EW_STRIDE];
    float4 v6 = x[t + (8 * o + 6) * EW_STRIDE];
    float4 v7 = x[t + (8 * o + 7) * EW_STRIDE];
    qx[t + (8 * o + 0) * EW_STRIDE] = quant4(v0, sx);
    qx[t + (8 * o + 1) * EW_STRIDE] = quant4(v1, sx);
    qx[t + (8 * o + 2) * EW_STRIDE] = quant4(v2, sx);
    qx[t + (8 * o + 3) * EW_STRIDE] = quant4(v3, sx);
    qx[t + (8 * o + 4) * EW_STRIDE] = quant4(v4, sx);
    qx[t + (8 * o + 5) * EW_STRIDE] = quant4(v5, sx);
    qx[t + (8 * o + 6) * EW_STRIDE] = quant4(v6, sx);
    qx[t + (8 * o + 7) * EW_STRIDE] = quant4(v7, sx);
  }
  {
    float4 v0 = w[t + 0 * EW_STRIDE];
    float4 v1 = w[t + 1 * EW_STRIDE];
    float4 v2 = w[t + 2 * EW_STRIDE];
    float4 v3 = w[t + 3 * EW_STRIDE];
    float4 v4 = w[t + 4 * EW_STRIDE];
    float4 v5 = w[t + 5 * EW_STRIDE];
    float4 v6 = w[t + 6 * EW_STRIDE];
    float4 v7 = w[t + 7 * EW_STRIDE];
    qw[t + 0 * EW_STRIDE] = quant4(v0, sw);
    qw[t + 1 * EW_STRIDE] = quant4(v1, sw);
    qw[t + 2 * EW_STRIDE] = quant4(v2, sw);
    qw[t + 3 * EW_STRIDE] = quant4(v3, sw);
    qw[t + 4 * EW_STRIDE] = quant4(v4, sw);
    qw[t + 5 * EW_STRIDE] = quant4(v5, sw);
    qw[t + 6 * EW_STRIDE] = quant4(v6, sw);
    qw[t + 7 * EW_STRIDE] = quant4(v7, sw);
  }
}

// ---------------------------------------------------------------------------
// 256x256 8-phase i8 GEMM — EXACT R1 revert (proven 139 us, MfmaUtil 43%,
// bank conflicts 0). SYNC_MID keeps the explicit lgkmcnt(0)+sched_barrier(0):
// R2 showed that removing them lets the compiler resink DMA issues / ds_reads
// around the bare s_barrier builtins and regresses the schedule.
// ---------------------------------------------------------------------------
#define BM 256
#define BN 256
#define BKB 128
#define HALF 16384
#define NIT 15  // main iterations; last iteration (tiles 30,31) is peeled

#define LDSA(buf) (lds + ((buf) * 4 + wm) * HALF)
#define LDSB(buf) (lds + ((buf) * 4 + 2 + (wn >> 1)) * HALF)

#define STG_A(buf, h, kt)                                          \
  {                                                                \
    signed char* d = lds + ((buf) * 4 + (h)) * HALF + wdst;        \
    const signed char* s = aS + (h) * HSK + (size_t)(kt) * BKB;    \
    async_load16(s, d);                                            \
    async_load16(s + 64 * (size_t)Kdim, d + 8192);                 \
  }
#define STG_B(buf, h, kt)                                          \
  {                                                                \
    signed char* d = lds + ((buf) * 4 + 2 + (h)) * HALF + wdst;    \
    const signed char* s = bS + (h) * HSK + (size_t)(kt) * BKB;    \
    async_load16(s, d);                                            \
    async_load16(s + 64 * (size_t)Kdim, d + 8192);                 \
  }

#define LOAD_A(buf, mh)                                            \
  {                                                                \
    const signed char* ab = LDSA(buf) + (mh) * 8192;               \
    _Pragma("unroll") for (int mi = 0; mi < 4; mi++) {             \
      afr[mi][0] = *(const int32x4*)(ab + mi * 2048 + aoff0);      \
      afr[mi][1] = *(const int32x4*)(ab + mi * 2048 + aoff1);      \
    }                                                              \
  }
#define LOAD_B(buf, g)                                             \
  {                                                                \
    const signed char* bb = LDSB(buf) + brow0 + (g) * 4096;        \
    _Pragma("unroll") for (int j = 0; j < 2; j++) {                \
      bfr[(g) * 2 + j][0] = *(const int32x4*)(bb + j * 2048 + aoff0); \
      bfr[(g) * 2 + j][1] = *(const int32x4*)(bb + j * 2048 + aoff1); \
    }                                                              \
  }

#define MFMA_Q(ma, nb)                                                        \
  _Pragma("unroll") for (int mi = 0; mi < 4; mi++)                            \
  _Pragma("unroll") for (int nj = 0; nj < 2; nj++)                            \
  _Pragma("unroll") for (int ks = 0; ks < 2; ks++)                            \
      acc[(ma) * 4 + mi][(nb) * 2 + nj] =                                     \
          __builtin_amdgcn_mfma_i32_16x16x64_i8(                              \
              afr[mi][ks], bfr[(nb) * 2 + nj][ks],                            \
              acc[(ma) * 4 + mi][(nb) * 2 + nj], 0, 0, 0);

#define SYNC_MID()                                       \
  __builtin_amdgcn_s_barrier();                          \
  asm volatile("s_waitcnt lgkmcnt(0)" ::: "memory");     \
  __builtin_amdgcn_sched_barrier(0);                     \
  __builtin_amdgcn_s_setprio(1);

#define PH_END()                \
  __builtin_amdgcn_s_setprio(0); \
  __builtin_amdgcn_s_barrier();

#define PH_END_V(n)                                      \
  __builtin_amdgcn_s_setprio(0);                         \
  asm volatile("s_waitcnt vmcnt(" #n ")" ::: "memory");  \
  __builtin_amdgcn_s_barrier();

__global__ __launch_bounds__(512, 2) void gemm_i8_kernel(
    const signed char* __restrict__ Aq, const signed char* __restrict__ Bq,
    const float* __restrict__ bias, const int* __restrict__ amax_bits,
    float* __restrict__ out) {
  __shared__ signed char lds[8 * HALF];  // 128 KiB

  const int tid = threadIdx.x;
  const int lane = tid & 63;
  const int w = tid >> 6;
  const int wm = w >> 2;  // 0..1
  const int wn = w & 3;   // 0..3

  const int m0 = blockIdx.y * BM;
  const int n0 = blockIdx.x * BN;

  // staging: thread covers rows r0 and r0+64 of a half, same (swizzled) col
  const int r0 = tid >> 3;
  const int gcol = ((tid & 7) * 16) ^ ((r0 & 7) << 4);
  const signed char* aS = Aq + (size_t)(m0 + r0) * Kdim + gcol;
  const signed char* bS = Bq + (size_t)(n0 + r0) * Kdim + gcol;
  const size_t HSK = (size_t)128 * Kdim;
  const int wdst = w * 1024;  // wave-uniform LDS dest

  // ds-read offsets (row = lane&15 within frag; swizzle uses lane&7)
  const int aoff0 =
      (lane & 15) * 128 + (((lane >> 4) * 16) ^ ((lane & 7) << 4));
  const int aoff1 =
      (lane & 15) * 128 + ((64 + (lane >> 4) * 16) ^ ((lane & 7) << 4));
  const int brow0 = (wn & 1) * 8192;

  int32x4 acc[8][4] = {};
  int32x4 afr[4][2], bfr[4][2];

  // prologue: tile0 -> buf0 (all halves); tile1 B-halves -> buf1
  STG_A(0, 0, 0);
  STG_A(0, 1, 0);
  STG_B(0, 0, 0);
  STG_B(0, 1, 0);
  STG_B(1, 0, 1);
  STG_B(1, 1, 1);
  asm volatile("s_waitcnt vmcnt(4)" ::: "memory");
  __builtin_amdgcn_s_barrier();

#pragma unroll 1
  for (int it = 0; it < NIT; ++it) {
    const int kt1 = 2 * it + 1, kt2 = 2 * it + 2, kt3 = 2 * it + 3;
    // phase 0: tile 2i quadrant (0,0)
    LOAD_A(0, 0); LOAD_B(0, 0); STG_A(1, 0, kt1);
    SYNC_MID(); MFMA_Q(0, 0); PH_END();
    // phase 1
    LOAD_B(0, 1); STG_A(1, 1, kt1);
    SYNC_MID(); MFMA_Q(0, 1); PH_END();
    // phase 2
    LOAD_A(0, 1); STG_B(0, 0, kt2);
    SYNC_MID(); MFMA_Q(1, 1); PH_END();
    // phase 3 (counted wait: covers tile 2i+1 A/B for phase 4)
    STG_B(0, 1, kt2);
    SYNC_MID(); MFMA_Q(1, 0); PH_END_V(4);
    // phase 4: tile 2i+1 quadrant (0,0)
    LOAD_A(1, 0); LOAD_B(1, 0); STG_A(0, 0, kt2);
    SYNC_MID(); MFMA_Q(0, 0); PH_END();
    // phase 5
    LOAD_B(1, 1); STG_A(0, 1, kt2);
    SYNC_MID(); MFMA_Q(0, 1); PH_END();
    // phase 6
    LOAD_A(1, 1); STG_B(1, 0, kt3);
    SYNC_MID(); MFMA_Q(1, 1); PH_END();
    // phase 7 (counted wait: covers tile 2i+2 for next iter phase 0)
    STG_B(1, 1, kt3);
    SYNC_MID(); MFMA_Q(1, 0); PH_END_V(4);
  }

  // peeled last iteration: tiles 30 (buf0) / 31 (buf1); only stage 31's A
  {
    LOAD_A(0, 0); LOAD_B(0, 0); STG_A(1, 0, 31);
    SYNC_MID(); MFMA_Q(0, 0); PH_END();
    LOAD_B(0, 1); STG_A(1, 1, 31);
    SYNC_MID(); MFMA_Q(0, 1); PH_END();
    LOAD_A(0, 1);
    SYNC_MID(); MFMA_Q(1, 1); PH_END();
    SYNC_MID(); MFMA_Q(1, 0); PH_END_V(0);  // full drain: no DMA in flight
    LOAD_A(1, 0); LOAD_B(1, 0);
    SYNC_MID(); MFMA_Q(0, 0); PH_END();
    LOAD_B(1, 1);
    SYNC_MID(); MFMA_Q(0, 1); PH_END();
    LOAD_A(1, 1);
    SYNC_MID(); MFMA_Q(1, 1); PH_END();
    SYNC_MID(); MFMA_Q(1, 0);
    __builtin_amdgcn_s_setprio(0);
  }

  // epilogue: dequant + bias, scalar stores coalesced across lanes
  const float sx = MAXV / __int_as_float(amax_bits[0]);
  const float sw = MAXV / __int_as_float(amax_bits[1]);
  const float inv = 1.0f / (sx * sw);
  const int crow = (lane >> 4) * 4;
  const int ccol = lane & 15;
#pragma unroll
  for (int nj = 0; nj < 4; nj++) {
    const int n = n0 + wn * 64 + nj * 16 + ccol;
    const float bv = bias[n];
#pragma unroll
    for (int a = 0; a < 8; a++) {
      const int m = m0 + wm * 128 + a * 16 + crow;
      float* op = out + (size_t)m * Ndim + n;
#pragma unroll
      for (int r = 0; r < 4; r++)
        op[(size_t)r * Ndim] = (float)acc[a][nj][r] * inv + bv;
    }
  }
}

extern "C" void kernel_launch(void* const* d_in, const int* in_sizes, int n_in,
                              void* d_out, int out_size, void* d_ws,
                              size_t ws_size, hipStream_t stream) {
  const float* x = (const float*)d_in[0];
  const float* wgt = (const float*)d_in[1];
  const float* bias = (const float*)d_in[2];
  float* out = (float*)d_out;

  int* amax = (int*)d_ws;
  signed char* qx = (signed char*)d_ws + 256;
  signed char* qw = qx + (size_t)Mdim * Kdim;

  hipMemsetAsync(amax, 0, 2 * sizeof(int), stream);
  hipLaunchKernelGGL(amax_both_kernel, dim3(EW_GRID), dim3(EW_BLOCK), 0, stream,
                     (const float4*)x, (const float4*)wgt, amax);
  hipLaunchKernelGGL(quant_both_kernel, dim3(EW_GRID), dim3(EW_BLOCK), 0,
                     stream, (const float4*)x, (const float4*)wgt, amax,
                     (char4*)qx, (char4*)qw);
  hipLaunchKernelGGL(gemm_i8_kernel, dim3(Ndim / BN, Mdim / BM), dim3(512), 0,
                     stream, qx, qw, bias, amax, out);
}